// Round 3
// baseline (425.369 us; speedup 1.0000x reference)
//
#include <hip/hip_runtime.h>
#include <math.h>

#define NL 7

// One block per (b, i). 4 waves; wave dd owns neighbor offset
// dj in {-2,-1,+1,+2}. Each lane = one (ai,aj) of its 8x8 tile, evolving all
// 8 channels through the 7-layer conv stack. Conv halo (aj +/- 1) comes from
// wave shuffles — no LDS, no barriers in the conv loop. Only the nonzero
// 32-B output segments are written; zeros come from a prior hipMemsetAsync.
__global__ __launch_bounds__(256) void sparse_kernel(
    const float* __restrict__ pw,      // (64, 1024, 1024)
    const float* __restrict__ conv_w,  // (7, 8, 8, 1, 3)
    const float* __restrict__ conv_b,  // (7, 8)
    const float* __restrict__ prelu_a, // (7,)
    float* __restrict__ out)           // (64, 1024, 1024), pre-zeroed
{
    __shared__ float wts[NL][8][8][3];
    __shared__ float bs[NL][8];
    __shared__ float al[NL];
    __shared__ float we_s[4][8][64];   // [dd][c][ai*8+aj]
    __shared__ float rowinv[64];       // [c*8+ai]

    const int b = blockIdx.x >> 7;
    const int i = blockIdx.x & 127;
    const int t = threadIdx.x;
    const int dd = t >> 6;             // wave id = neighbor slot
    const int lane = t & 63;
    const int ai = lane >> 3, aj = lane & 7;
    const int dj = (dd < 2) ? dd - 2 : dd - 1;   // -2,-1,+1,+2
    const int j = i + dj;
    const bool valid = (j >= 0) && (j < 128);

    // stage weights
    for (int p = t; p < NL * 8 * 8 * 3; p += 256) ((float*)wts)[p] = conv_w[p];
    for (int p = t; p < NL * 8; p += 256)         ((float*)bs)[p]  = conv_b[p];
    if (t < NL) al[t] = prelu_a[t];

    // load x tile (zeros for invalid neighbor)
    float x[8], h[8];
    const float* base = pw + (((size_t)(b * 8)) << 20)
                           + (size_t)(i * 8 + ai) * 1024
                           + (size_t)((valid ? j : 0) * 8 + aj);
    #pragma unroll
    for (int c = 0; c < 8; ++c) {
        x[c] = valid ? base[((size_t)c) << 20] : 0.f;
        h[c] = x[c];
    }

    __syncthreads();   // weights visible

    // 7-layer conv(1x3, pad 1 along aj) + bias + PReLU + residual.
    // Halo via shuffles: lane-1 / lane+1 stay within the wave; the 8-boundary
    // crossings are exactly aj==0 / aj==7 which are masked to zero (padding).
    for (int l = 0; l < NL; ++l) {
        float v0[8], v2[8];
        #pragma unroll
        for (int ci = 0; ci < 8; ++ci) {
            float up = __shfl_up(h[ci], 1, 64);
            float dn = __shfl_down(h[ci], 1, 64);
            v0[ci] = (aj > 0) ? up : 0.f;
            v2[ci] = (aj < 7) ? dn : 0.f;
        }
        const float a = al[l];
        float nxt[8];
        #pragma unroll
        for (int co = 0; co < 8; ++co) {
            float acc = bs[l][co];
            #pragma unroll
            for (int ci = 0; ci < 8; ++ci) {
                acc += wts[l][co][ci][0] * v0[ci]
                     + wts[l][co][ci][1] * h[ci]
                     + wts[l][co][ci][2] * v2[ci];
            }
            float y = (acc >= 0.f) ? acc : a * acc;
            nxt[co] = y + h[co];
        }
        #pragma unroll
        for (int co = 0; co < 8; ++co) h[co] = nxt[co];
    }

    // gate -> we
    #pragma unroll
    for (int c = 0; c < 8; ++c) {
        float sg = 1.f / (1.f + __expf(-h[c]));
        float s = x[c] - sg;
        s = (s > 0.f) ? s : 0.f;
        float we = (valid && ai != aj) ? expm1f(s) : 0.f;
        we_s[dd][c][lane] = we;
    }
    __syncthreads();

    // row sums (row = (c, ai)): sum over the 4 neighbor tiles x 8 aj
    if (t < 64) {
        const int c = t >> 3, aii = t & 7;
        float s = 0.f;
        #pragma unroll
        for (int d2 = 0; d2 < 4; ++d2)
            #pragma unroll
            for (int a2 = 0; a2 < 8; ++a2)
                s += we_s[d2][c][aii * 8 + a2];
        rowinv[t] = 1.f / (s + 1e-5f);
    }
    __syncthreads();

    // write only the nonzero 8-float segments: wave dd writes its j-block,
    // lane = row (c, airow). 32 B per lane, 8.4 MB total across the grid.
    if (valid) {
        const int row = lane;          // 0..63 = c*8 + airow
        const int c = row >> 3, airow = row & 7;
        const float inv = rowinv[row];
        float4 lo, hi;
        lo.x = we_s[dd][c][airow * 8 + 0] * inv;
        lo.y = we_s[dd][c][airow * 8 + 1] * inv;
        lo.z = we_s[dd][c][airow * 8 + 2] * inv;
        lo.w = we_s[dd][c][airow * 8 + 3] * inv;
        hi.x = we_s[dd][c][airow * 8 + 4] * inv;
        hi.y = we_s[dd][c][airow * 8 + 5] * inv;
        hi.z = we_s[dd][c][airow * 8 + 6] * inv;
        hi.w = we_s[dd][c][airow * 8 + 7] * inv;
        float4* p = (float4*)(out + (((size_t)(b * 8 + c)) << 20)
                                  + (size_t)(i * 8 + airow) * 1024
                                  + (size_t)j * 8);
        p[0] = lo;
        p[1] = hi;
    }
}

extern "C" void kernel_launch(void* const* d_in, const int* in_sizes, int n_in,
                              void* d_out, int out_size, void* d_ws, size_t ws_size,
                              hipStream_t stream) {
    const float* pw      = (const float*)d_in[0];
    const float* conv_w  = (const float*)d_in[1];
    const float* conv_b  = (const float*)d_in[2];
    const float* prelu_a = (const float*)d_in[3];
    // scalars d_in[4..6] (bsz=8, cross_range=2, agent_num=8) baked in.
    (void)d_ws; (void)ws_size;

    // zero the output (97% of it stays zero), then fill the sparse band
    hipMemsetAsync(d_out, 0, (size_t)out_size * sizeof(float), stream);
    sparse_kernel<<<8 * 128, 256, 0, stream>>>(pw, conv_w, conv_b, prelu_a,
                                               (float*)d_out);
}

// Round 4
// 412.445 us; speedup vs baseline: 1.0313x; 1.0313x over previous
//
#include <hip/hip_runtime.h>
#include <math.h>

#define NL 7

// One block per (b, i). 4 waves; wave dd owns neighbor offset
// dj in {-2,-1,+1,+2}. Each lane = one (ai,aj) of its 8x8 tile, evolving all
// 8 channels through the 7-layer conv stack. Conv halo (aj +/- 1) via wave
// shuffles — no barriers in the conv loop. The block then writes its 64
// complete output rows (256 KB) exactly once, fully coalesced.
__global__ __launch_bounds__(256) void fused_kernel(
    const float* __restrict__ pw,      // (64, 1024, 1024)
    const float* __restrict__ conv_w,  // (7, 8, 8, 1, 3)
    const float* __restrict__ conv_b,  // (7, 8)
    const float* __restrict__ prelu_a, // (7,)
    float* __restrict__ out)           // (64, 1024, 1024)
{
    __shared__ float wts[NL][8][8][3];
    __shared__ float bs[NL][8];
    __shared__ float al[NL];
    __shared__ float we_s[4][8][64];   // [dd][c][ai*8+aj]
    __shared__ float rowinv[64];       // [c*8+ai]

    const int b = blockIdx.x >> 7;
    const int i = blockIdx.x & 127;
    const int t = threadIdx.x;
    const int dd = t >> 6;             // wave id = neighbor slot
    const int lane = t & 63;
    const int ai = lane >> 3, aj = lane & 7;
    const int dj = (dd < 2) ? dd - 2 : dd - 1;   // -2,-1,+1,+2
    const int j = i + dj;
    const bool valid = (j >= 0) && (j < 128);

    // stage weights
    for (int p = t; p < NL * 8 * 8 * 3; p += 256) ((float*)wts)[p] = conv_w[p];
    for (int p = t; p < NL * 8; p += 256)         ((float*)bs)[p]  = conv_b[p];
    if (t < NL) al[t] = prelu_a[t];

    // load x tile (zeros for invalid neighbor)
    float x[8], h[8];
    const float* base = pw + (((size_t)(b * 8)) << 20)
                           + (size_t)(i * 8 + ai) * 1024
                           + (size_t)((valid ? j : 0) * 8 + aj);
    #pragma unroll
    for (int c = 0; c < 8; ++c) {
        x[c] = valid ? base[((size_t)c) << 20] : 0.f;
        h[c] = x[c];
    }

    __syncthreads();   // weights visible

    // 7-layer conv(1x3, pad 1 along aj) + bias + PReLU + residual.
    // Halo via shuffles: aj+/-1 stays within the wave; the tile boundary
    // (aj==0 / aj==7) is exactly the conv zero-padding.
    for (int l = 0; l < NL; ++l) {
        float v0[8], v2[8];
        #pragma unroll
        for (int ci = 0; ci < 8; ++ci) {
            float up = __shfl_up(h[ci], 1, 64);
            float dn = __shfl_down(h[ci], 1, 64);
            v0[ci] = (aj > 0) ? up : 0.f;
            v2[ci] = (aj < 7) ? dn : 0.f;
        }
        const float a = al[l];
        float nxt[8];
        #pragma unroll
        for (int co = 0; co < 8; ++co) {
            float acc = bs[l][co];
            #pragma unroll
            for (int ci = 0; ci < 8; ++ci) {
                acc += wts[l][co][ci][0] * v0[ci]
                     + wts[l][co][ci][1] * h[ci]
                     + wts[l][co][ci][2] * v2[ci];
            }
            float y = (acc >= 0.f) ? acc : a * acc;
            nxt[co] = y + h[co];
        }
        #pragma unroll
        for (int co = 0; co < 8; ++co) h[co] = nxt[co];
    }

    // gate -> we
    #pragma unroll
    for (int c = 0; c < 8; ++c) {
        float sg = 1.f / (1.f + __expf(-h[c]));
        float s = x[c] - sg;
        s = (s > 0.f) ? s : 0.f;
        float we = (valid && ai != aj) ? expm1f(s) : 0.f;
        we_s[dd][c][lane] = we;
    }
    __syncthreads();

    // row sums (row = (c, ai)): sum over the 4 neighbor tiles x 8 aj
    if (t < 64) {
        const int c = t >> 3, aii = t & 7;
        float s = 0.f;
        #pragma unroll
        for (int d2 = 0; d2 < 4; ++d2)
            #pragma unroll
            for (int a2 = 0; a2 < 8; ++a2)
                s += we_s[d2][c][aii * 8 + a2];
        rowinv[t] = 1.f / (s + 1e-5f);
    }
    __syncthreads();

    // Write the 64 output rows of this (b, i): one full 4 KB row per
    // iteration, 256 threads x float4, perfectly coalesced. Each row has
    // <=8 nonzero float4s (the j = i+/-1, i+/-2 blocks), rest are zeros.
    const int col4 = t;                 // float4 index within a row
    const int jc = col4 >> 1;           // j-block of this float4
    const int djc = jc - i;
    const bool inband = (djc >= -2) && (djc <= 2) && (djc != 0);
    const int d2 = (djc < 0) ? djc + 2 : djc + 1;   // valid only if inband
    const int half = (col4 & 1) * 4;

    for (int row = 0; row < 64; ++row) {
        const int c = row >> 3, airow = row & 7;
        const float inv = rowinv[row];
        float4 v = make_float4(0.f, 0.f, 0.f, 0.f);
        if (inband) {
            const float* p = &we_s[d2][c][airow * 8 + half];
            v.x = p[0] * inv; v.y = p[1] * inv;
            v.z = p[2] * inv; v.w = p[3] * inv;
        }
        float4* rowp = (float4*)(out + (((size_t)(b * 8 + c)) << 20)
                                     + (size_t)(i * 8 + airow) * 1024);
        rowp[col4] = v;
    }
}

extern "C" void kernel_launch(void* const* d_in, const int* in_sizes, int n_in,
                              void* d_out, int out_size, void* d_ws, size_t ws_size,
                              hipStream_t stream) {
    const float* pw      = (const float*)d_in[0];
    const float* conv_w  = (const float*)d_in[1];
    const float* conv_b  = (const float*)d_in[2];
    const float* prelu_a = (const float*)d_in[3];
    // scalars d_in[4..6] (bsz=8, cross_range=2, agent_num=8) baked in.
    (void)d_ws; (void)ws_size;

    fused_kernel<<<8 * 128, 256, 0, stream>>>(pw, conv_w, conv_b, prelu_a,
                                              (float*)d_out);
}